// Round 1
// baseline (269.910 us; speedup 1.0000x reference)
//
#include <hip/hip_runtime.h>
#include <math.h>

#define NROWS 16384
#define DT_C 0.01f

// ---------------------------------------------------------------------------
// Generic f32 GEMM: C[row, col] = relu( A[M,K] @ W[K, ldw](+cols col0..) + bias )
// 64x64 tile per block, 256 threads, 4x4 register blocking, BK=16.
// Optional rank-1 omega term (layer1's 257th input column).
// ---------------------------------------------------------------------------
__global__ __launch_bounds__(256) void gemm_relu_k(
    const float* __restrict__ A, const float* __restrict__ W,
    const float* __restrict__ bias, float* __restrict__ C,
    int K, int ldw, int ldc,
    const float* __restrict__ omega, const float* __restrict__ wOmega)
{
    __shared__ float As[16][68];   // [k][m], padded: 2-way max bank conflict, 16B-aligned rows
    __shared__ float Bs[16][64];   // [k][n]

    const int tid  = threadIdx.x;
    const int row0 = blockIdx.x * 64;
    const int col0 = blockIdx.y * 64;
    const int tm = tid >> 4;       // 0..15 -> rows tm*4..tm*4+3
    const int tn = tid & 15;       // 0..15 -> cols tn*4..tn*4+3

    float acc[4][4];
    {
        float b4[4];
        #pragma unroll
        for (int j = 0; j < 4; ++j) b4[j] = bias[col0 + tn * 4 + j];
        if (omega) {
            float om[4], wo[4];
            #pragma unroll
            for (int i = 0; i < 4; ++i) om[i] = omega[row0 + tm * 4 + i];
            #pragma unroll
            for (int j = 0; j < 4; ++j) wo[j] = wOmega[col0 + tn * 4 + j];
            #pragma unroll
            for (int i = 0; i < 4; ++i)
                #pragma unroll
                for (int j = 0; j < 4; ++j)
                    acc[i][j] = fmaf(om[i], wo[j], b4[j]);
        } else {
            #pragma unroll
            for (int i = 0; i < 4; ++i)
                #pragma unroll
                for (int j = 0; j < 4; ++j)
                    acc[i][j] = b4[j];
        }
    }

    // staging indices
    const int am = tid >> 2;            // 0..63 (row within tile)
    const int ak = (tid & 3) * 4;       // k offset 0,4,8,12
    const int bk = tid >> 4;            // 0..15 (k row)
    const int bc = (tid & 15) * 4;      // col offset
    const float* Aptr = A + (size_t)(row0 + am) * K + ak;
    const float* Wptr = W + (size_t)bk * ldw + col0 + bc;

    for (int kb = 0; kb < K; kb += 16) {
        __syncthreads();
        float4 av = *(const float4*)(Aptr + kb);
        float4 bv = *(const float4*)(Wptr + (size_t)kb * ldw);
        As[ak + 0][am] = av.x;
        As[ak + 1][am] = av.y;
        As[ak + 2][am] = av.z;
        As[ak + 3][am] = av.w;
        *(float4*)&Bs[bk][bc] = bv;
        __syncthreads();
        #pragma unroll
        for (int k = 0; k < 16; ++k) {
            float4 a4 = *(const float4*)&As[k][tm * 4];
            float4 b4 = *(const float4*)&Bs[k][tn * 4];
            float ar[4] = {a4.x, a4.y, a4.z, a4.w};
            float br[4] = {b4.x, b4.y, b4.z, b4.w};
            #pragma unroll
            for (int i = 0; i < 4; ++i)
                #pragma unroll
                for (int j = 0; j < 4; ++j)
                    acc[i][j] = fmaf(ar[i], br[j], acc[i][j]);
        }
    }

    #pragma unroll
    for (int i = 0; i < 4; ++i) {
        const int row = row0 + tm * 4 + i;
        float4 o;
        o.x = fmaxf(acc[i][0], 0.f);
        o.y = fmaxf(acc[i][1], 0.f);
        o.z = fmaxf(acc[i][2], 0.f);
        o.w = fmaxf(acc[i][3], 0.f);
        *(float4*)&C[(size_t)row * ldc + col0 + tn * 4] = o;
    }
}

// ---------------------------------------------------------------------------
// Per-row 128-dot heads: xi_mean = softplus(hm . Wm2 + bm2), xi_lnvar = hl . Wl2 + bl2
// hmhl: N x 256 (cols 0..127 = hm, 128..255 = hl). One wave per row.
// ---------------------------------------------------------------------------
__global__ __launch_bounds__(256) void head_dot_k(
    const float* __restrict__ hmhl,
    const float* __restrict__ Wm2, const float* __restrict__ bm2,
    const float* __restrict__ Wl2, const float* __restrict__ bl2,
    float* __restrict__ out_mean, float* __restrict__ out_lnvar)
{
    const int g    = blockIdx.x * 4 + (threadIdx.x >> 6);   // row
    const int lane = threadIdx.x & 63;
    const float* hrow = hmhl + (size_t)g * 256;

    float pm = hrow[lane] * Wm2[lane] + hrow[lane + 64] * Wm2[lane + 64];
    float pl = hrow[lane + 128] * Wl2[lane] + hrow[lane + 192] * Wl2[lane + 64];
    #pragma unroll
    for (int m = 32; m > 0; m >>= 1) {
        pm += __shfl_xor(pm, m);
        pl += __shfl_xor(pl, m);
    }
    if (lane == 0) {
        float xm = pm + bm2[0];
        // stable softplus = max(x,0) + log1p(exp(-|x|))
        out_mean[g]  = fmaxf(xm, 0.f) + log1pf(expf(-fabsf(xm)));
        out_lnvar[g] = pl + bl2[0];
    }
}

// ---------------------------------------------------------------------------
// ODE scan + decay, fused. 16 lanes per row (4 hidden units each), 16 rows/block.
// y_seq staged in LDS with decay pre-applied; coalesced float4 store at the end.
// ---------------------------------------------------------------------------
__global__ __launch_bounds__(256) void ode_k(
    const float* __restrict__ data, const float* __restrict__ omega_g,
    const float* __restrict__ eps_g,
    const float* __restrict__ W1, const float* __restrict__ b1,
    const float* __restrict__ W2, const float* __restrict__ b2p,
    const float* __restrict__ xmean, const float* __restrict__ xlnv,
    float* __restrict__ xout)
{
    __shared__ float ybuf[16][260];   // pad 260: conflict-light, rows stay 16B-aligned

    const int tid = threadIdx.x;
    const int r   = tid >> 4;    // row within block, 0..15
    const int l   = tid & 15;    // lane within row
    const int row = blockIdx.x * 16 + r;

    // per-lane weights: hidden units l*4 .. l*4+3 (held in 16 VGPRs)
    const float4 w0 = *(const float4*)&W1[l * 4];        // W_aux1[0][:]  (omega weights)
    const float4 w1 = *(const float4*)&W1[64 + l * 4];   // W_aux1[1][:]  (y weights)
    const float4 bb = *(const float4*)&b1[l * 4];
    const float4 w2 = *(const float4*)&W2[l * 4];
    const float  b2 = b2p[0];

    const float om = omega_g[row];
    const float ep = eps_g[row];
    float xi = xmean[row] + expf(0.5f * xlnv[row]) * ep;
    xi = fminf(fmaxf(xi, 0.f), 1.f);
    const float s = expf(-xi * DT_C);   // per-step decay factor

    float y = data[(size_t)row * 256];  // data[:,0]
    float v = 0.f;
    float d = 1.f;

    for (int t = 0; t < 256; ++t) {
        float h0 = fmaxf(fmaf(om, w0.x, fmaf(y, w1.x, bb.x)), 0.f);
        float h1 = fmaxf(fmaf(om, w0.y, fmaf(y, w1.y, bb.y)), 0.f);
        float h2 = fmaxf(fmaf(om, w0.z, fmaf(y, w1.z, bb.z)), 0.f);
        float h3 = fmaxf(fmaf(om, w0.w, fmaf(y, w1.w, bb.w)), 0.f);
        float p = fmaf(h3, w2.w, fmaf(h2, w2.z, fmaf(h1, w2.y, h0 * w2.x)));
        p += __shfl_xor(p, 1);
        p += __shfl_xor(p, 2);
        p += __shfl_xor(p, 4);
        p += __shfl_xor(p, 8);
        const float acc = p + b2;
        if (l == 0) ybuf[r][t] = d * y;   // store y_t with decay applied
        d *= s;
        const float yn = fmaf(DT_C, v, y);   // y_{t+1} = y_t + DT*v_t
        v = fmaf(DT_C, acc, v);              // v_{t+1} = v_t + DT*acc(y_t)
        y = yn;
    }
    __syncthreads();

    // coalesced store: 16-lane groups cover 64 contiguous floats per row segment
    const int rr = tid >> 4;
    const int cc = (tid & 15) * 4;
    float* dst = xout + ((size_t)blockIdx.x * 16 + rr) * 256 + cc;
    #pragma unroll
    for (int i = 0; i < 4; ++i) {
        float4 vv = *(const float4*)&ybuf[rr][cc + 64 * i];
        *(float4*)&dst[64 * i] = vv;
    }
}

// ---------------------------------------------------------------------------
extern "C" void kernel_launch(void* const* d_in, const int* in_sizes, int n_in,
                              void* d_out, int out_size, void* d_ws, size_t ws_size,
                              hipStream_t stream)
{
    const float* data    = (const float*)d_in[0];
    const float* omega   = (const float*)d_in[1];
    const float* eps     = (const float*)d_in[2];
    const float* W_feat1 = (const float*)d_in[3];
    const float* b_feat1 = (const float*)d_in[4];
    const float* W_feat2 = (const float*)d_in[5];
    const float* b_feat2 = (const float*)d_in[6];
    const float* W_xim1  = (const float*)d_in[7];
    const float* b_xim1  = (const float*)d_in[8];
    const float* W_xim2  = (const float*)d_in[9];
    const float* b_xim2  = (const float*)d_in[10];
    const float* W_xil1  = (const float*)d_in[11];
    const float* b_xil1  = (const float*)d_in[12];
    const float* W_xil2  = (const float*)d_in[13];
    const float* b_xil2  = (const float*)d_in[14];
    const float* W_aux1  = (const float*)d_in[15];
    const float* b_aux1  = (const float*)d_in[16];
    const float* W_aux2  = (const float*)d_in[17];
    const float* b_aux2  = (const float*)d_in[18];

    float* out_mean  = (float*)d_out;
    float* out_lnvar = out_mean + NROWS;
    float* out_x     = out_lnvar + NROWS;

    float* h1   = (float*)d_ws;                       // N x 256
    float* feat = h1 + (size_t)NROWS * 256;           // N x 256
    float* hmhl = h1;                                 // reuse h1 after GEMM2

    dim3 blk(256);

    // layer1: h1 = relu([data, omega] @ W_feat1 + b)   (omega = 257th row of W)
    gemm_relu_k<<<dim3(256, 4), blk, 0, stream>>>(
        data, W_feat1, b_feat1, h1, 256, 256, 256, omega, W_feat1 + 256 * 256);
    // layer2: feat = relu(h1 @ W_feat2 + b)
    gemm_relu_k<<<dim3(256, 4), blk, 0, stream>>>(
        h1, W_feat2, b_feat2, feat, 256, 256, 256, nullptr, nullptr);
    // heads: hm -> hmhl[:, 0:128], hl -> hmhl[:, 128:256]
    gemm_relu_k<<<dim3(256, 2), blk, 0, stream>>>(
        feat, W_xim1, b_xim1, hmhl, 256, 128, 256, nullptr, nullptr);
    gemm_relu_k<<<dim3(256, 2), blk, 0, stream>>>(
        feat, W_xil1, b_xil1, hmhl + 128, 256, 128, 256, nullptr, nullptr);
    // per-row dots -> xi_mean (softplus), xi_lnvar
    head_dot_k<<<4096, blk, 0, stream>>>(
        hmhl, W_xim2, b_xim2, W_xil2, b_xil2, out_mean, out_lnvar);
    // ODE scan + decay -> x_PAB
    ode_k<<<1024, blk, 0, stream>>>(
        data, omega, eps, W_aux1, b_aux1, W_aux2, b_aux2,
        out_mean, out_lnvar, out_x);
}

// Round 2
// 174.654 us; speedup vs baseline: 1.5454x; 1.5454x over previous
//
#include <hip/hip_runtime.h>
#include <math.h>

#define NROWS 16384
#define DT_C 0.01f

typedef short s16x8 __attribute__((ext_vector_type(8)));
typedef float f32x4 __attribute__((ext_vector_type(4)));

__device__ __forceinline__ unsigned short f2bf(float f) {
    unsigned u = __float_as_uint(f);
    u += 0x7fffu + ((u >> 16) & 1u);
    return (unsigned short)(u >> 16);
}
__device__ __forceinline__ float swz1(float v){ return __int_as_float(__builtin_amdgcn_ds_swizzle(__float_as_int(v), 0x041F)); }
__device__ __forceinline__ float swz2(float v){ return __int_as_float(__builtin_amdgcn_ds_swizzle(__float_as_int(v), 0x081F)); }
__device__ __forceinline__ float swz4(float v){ return __int_as_float(__builtin_amdgcn_ds_swizzle(__float_as_int(v), 0x101F)); }

// ---------------------------------------------------------------------------
// Prep: pack all stage-B weights into bf16 "LDS image" layout:
//   wpack[((s*32 + k8)*256 + n)*8 + j]  where k = k8*8 + j
// s=0: W_feat1[0:256][256], s=1: W_feat2, s=2: [W_xim1 | W_xil1] combined.
// Also build combined head bias biasH[256] = [b_xim1 | b_xil1].
// ---------------------------------------------------------------------------
__global__ __launch_bounds__(256) void prep_k(
    const float* __restrict__ Wf1, const float* __restrict__ Wf2,
    const float* __restrict__ Wm1, const float* __restrict__ Wl1,
    const float* __restrict__ bm1, const float* __restrict__ bl1,
    unsigned short* __restrict__ wpack, float* __restrict__ biasH)
{
    const int id = blockIdx.x * 256 + threadIdx.x;   // 0..24575
    const int n  = id & 255;
    const int k8 = (id >> 8) & 31;
    const int s  = id >> 13;

    unsigned short tmp[8];
    #pragma unroll
    for (int j = 0; j < 8; ++j) {
        const int k = k8 * 8 + j;
        float v;
        if (s == 0)      v = Wf1[k * 256 + n];
        else if (s == 1) v = Wf2[k * 256 + n];
        else             v = (n < 128) ? Wm1[k * 128 + n] : Wl1[k * 128 + n - 128];
        tmp[j] = f2bf(v);
    }
    *(uint4*)&wpack[((s * 32 + k8) * 256 + n) * 8] = *(const uint4*)tmp;

    if (id < 256) biasH[id] = (id < 128) ? bm1[id] : bl1[id - 128];
}

// ---------------------------------------------------------------------------
// Mega kernel: per 32-row block, runs
//   h1 = relu([data,w]@W1+b1)  -> LDS (bf16 packed frags)
//   feat = relu(h1@W2+b2)      -> LDS
//   heads = relu(feat@[Wm1|Wl1]+bH) -> LDS (f32, bank-rotated)
//   xi_mean = softplus(hm.Wm2+bm2), xi_lnvar = hl.Wl2+bl2
// MFMA 16x16x32 bf16. Block tile 32(M) x 256(N), K=256 in 64-chunks.
// Each wave owns a 64-col slice; A-frags shared via LDS.
// ---------------------------------------------------------------------------
__global__ __launch_bounds__(256, 2) void mega_k(
    const float* __restrict__ data, const float* __restrict__ omega,
    const unsigned short* __restrict__ wpack, const float* __restrict__ biasH,
    const float* __restrict__ bf1, const float* __restrict__ bf2,
    const float* __restrict__ w256g,
    const float* __restrict__ Wm2, const float* __restrict__ bm2,
    const float* __restrict__ Wl2, const float* __restrict__ bl2,
    float* __restrict__ out_mean, float* __restrict__ out_lnvar)
{
    __shared__ unsigned short As1[8192];   // 16KB: data frags; later feat frags
    __shared__ unsigned short Hs[8192];    // 16KB: h1 frags
    __shared__ unsigned short Bs[16384];   // 32KB: streamed B chunk; later heads f32
    __shared__ float omg[32];

    const int tid  = threadIdx.x;
    const int wid  = tid >> 6;
    const int lane = tid & 63;
    const int ln   = lane & 15;
    const int quad = lane >> 4;
    const int r0   = blockIdx.x * 32;

    // ---- stage A: data f32 -> As1 packed bf16 [kblk32][m32][8]
    {
        const int m = tid & 31, kb2 = tid >> 5;
        #pragma unroll
        for (int g = 0; g < 4; ++g) {
            const int kblk = kb2 + g * 8;
            const float4 v0 = *(const float4*)&data[(size_t)(r0 + m) * 256 + kblk * 8];
            const float4 v1 = *(const float4*)&data[(size_t)(r0 + m) * 256 + kblk * 8 + 4];
            unsigned short* d = &As1[(kblk * 32 + m) * 8];
            d[0]=f2bf(v0.x); d[1]=f2bf(v0.y); d[2]=f2bf(v0.z); d[3]=f2bf(v0.w);
            d[4]=f2bf(v1.x); d[5]=f2bf(v1.y); d[6]=f2bf(v1.z); d[7]=f2bf(v1.w);
        }
        if (tid < 32) omg[tid] = omega[r0 + tid];
    }

    f32x4 acc[2][4];

    auto seed = [&](const float* bias) {
        #pragma unroll
        for (int nt = 0; nt < 4; ++nt) {
            const float b = bias[wid * 64 + nt * 16 + ln];
            acc[0][nt] = f32x4{b, b, b, b};
            acc[1][nt] = acc[0][nt];
        }
    };

    auto run_stage = [&](const unsigned short* Ap, const unsigned short* wp) {
        for (int c = 0; c < 4; ++c) {
            __syncthreads();                       // prior Bs consumers done
            {
                const uint4* src = (const uint4*)(wp + c * 16384) + tid * 8;
                uint4* dst = (uint4*)Bs + tid * 8;
                #pragma unroll
                for (int i = 0; i < 8; ++i) dst[i] = src[i];
            }
            __syncthreads();
            #pragma unroll
            for (int kk = 0; kk < 2; ++kk) {
                const int kb = kk * 4 + quad;
                s16x8 a0 = *(const s16x8*)&Ap[((c * 8 + kb) * 32 + ln) * 8];
                s16x8 a1 = *(const s16x8*)&Ap[((c * 8 + kb) * 32 + 16 + ln) * 8];
                #pragma unroll
                for (int nt = 0; nt < 4; ++nt) {
                    s16x8 b = *(const s16x8*)&Bs[(kb * 256 + wid * 64 + nt * 16 + ln) * 8];
                    acc[0][nt] = __builtin_amdgcn_mfma_f32_16x16x32_bf16(a0, b, acc[0][nt], 0, 0, 0);
                    acc[1][nt] = __builtin_amdgcn_mfma_f32_16x16x32_bf16(a1, b, acc[1][nt], 0, 0, 0);
                }
            }
        }
    };

    // relu + bf16 + store to packed-frag LDS (optionally add omega rank-1 term)
    auto write_packed = [&](unsigned short* dst, bool addOm) {
        #pragma unroll
        for (int nt = 0; nt < 4; ++nt) {
            const int col = wid * 64 + nt * 16 + ln;
            const float wo = addOm ? w256g[col] : 0.f;
            #pragma unroll
            for (int mt = 0; mt < 2; ++mt) {
                #pragma unroll
                for (int r = 0; r < 4; ++r) {
                    const int row = mt * 16 + quad * 4 + r;
                    float v = acc[mt][nt][r];
                    if (addOm) v = fmaf(omg[row], wo, v);
                    v = fmaxf(v, 0.f);
                    dst[((col >> 3) * 32 + row) * 8 + (col & 7)] = f2bf(v);
                }
            }
        }
    };

    // stage 1: h1
    seed(bf1);
    run_stage(As1, wpack);
    write_packed(Hs, true);
    // stage 2: feat (overwrites As1 region)
    seed(bf2);
    run_stage(Hs, wpack + 65536);
    write_packed(As1, false);
    // stage 3: heads
    seed(biasH);
    run_stage(As1, wpack + 131072);
    __syncthreads();                               // all waves done reading Bs
    float* headsF = (float*)Bs;                    // [32][256] f32, col-rotated by 8*row
    #pragma unroll
    for (int nt = 0; nt < 4; ++nt) {
        const int col = wid * 64 + nt * 16 + ln;
        #pragma unroll
        for (int mt = 0; mt < 2; ++mt) {
            #pragma unroll
            for (int r = 0; r < 4; ++r) {
                const int row = mt * 16 + quad * 4 + r;
                headsF[row * 256 + ((col + row * 8) & 255)] = fmaxf(acc[mt][nt][r], 0.f);
            }
        }
    }
    __syncthreads();

    // ---- 128-dot heads: 8 lanes per row
    {
        const int m = tid >> 3, l = tid & 7;
        float pm = 0.f, pl = 0.f;
        #pragma unroll
        for (int q = 0; q < 4; ++q) {
            const int c0 = l * 16 + q * 4;
            const float4 hm = *(const float4*)&headsF[m * 256 + ((c0 + m * 8) & 255)];
            const float4 wm = *(const float4*)&Wm2[c0];
            const float4 hl = *(const float4*)&headsF[m * 256 + ((128 + c0 + m * 8) & 255)];
            const float4 wl = *(const float4*)&Wl2[c0];
            pm = fmaf(hm.w, wm.w, fmaf(hm.z, wm.z, fmaf(hm.y, wm.y, fmaf(hm.x, wm.x, pm))));
            pl = fmaf(hl.w, wl.w, fmaf(hl.z, wl.z, fmaf(hl.y, wl.y, fmaf(hl.x, wl.x, pl))));
        }
        pm += swz1(pm); pm += swz2(pm); pm += swz4(pm);
        pl += swz1(pl); pl += swz2(pl); pl += swz4(pl);
        if (l == 0) {
            const float xm = pm + bm2[0];
            out_mean[r0 + m]  = fmaxf(xm, 0.f) + log1pf(expf(-fabsf(xm)));
            out_lnvar[r0 + m] = pl + bl2[0];
        }
    }
}

// ---------------------------------------------------------------------------
// ODE scan + decay. 8 lanes/row x 8 hidden units/lane, 32 rows/block.
// a_u = om*w0_u + b1_u prefolded; b2 folded into reduction seed.
// ---------------------------------------------------------------------------
__global__ __launch_bounds__(256, 2) void ode_k(
    const float* __restrict__ data, const float* __restrict__ omega_g,
    const float* __restrict__ eps_g,
    const float* __restrict__ W1, const float* __restrict__ b1,
    const float* __restrict__ W2, const float* __restrict__ b2p,
    const float* __restrict__ xmean, const float* __restrict__ xlnv,
    float* __restrict__ xout)
{
    __shared__ float ybuf[32][260];   // 260: 16B-aligned rows, conflict-free step writes

    const int tid = threadIdx.x;
    const int r   = tid >> 3;    // row in block 0..31
    const int l   = tid & 7;     // lane in row
    const int row = blockIdx.x * 32 + r;

    const float4 w0a = *(const float4*)&W1[l * 8];
    const float4 w0b = *(const float4*)&W1[l * 8 + 4];
    const float4 w1a = *(const float4*)&W1[64 + l * 8];
    const float4 w1b = *(const float4*)&W1[64 + l * 8 + 4];
    const float4 bba = *(const float4*)&b1[l * 8];
    const float4 bbb = *(const float4*)&b1[l * 8 + 4];
    const float4 w2a = *(const float4*)&W2[l * 8];
    const float4 w2b = *(const float4*)&W2[l * 8 + 4];

    const float om = omega_g[row];
    const float ep = eps_g[row];
    float xi = xmean[row] + expf(0.5f * xlnv[row]) * ep;
    xi = fminf(fmaxf(xi, 0.f), 1.f);
    const float s = expf(-xi * DT_C);
    const float pseed = b2p[0] * 0.125f;

    // prefold omega into hidden bias
    float a0 = fmaf(om, w0a.x, bba.x), a1 = fmaf(om, w0a.y, bba.y);
    float a2 = fmaf(om, w0a.z, bba.z), a3 = fmaf(om, w0a.w, bba.w);
    float a4 = fmaf(om, w0b.x, bbb.x), a5 = fmaf(om, w0b.y, bbb.y);
    float a6 = fmaf(om, w0b.z, bbb.z), a7 = fmaf(om, w0b.w, bbb.w);

    float y = data[(size_t)row * 256];
    float v = 0.f;
    float d = 1.f;

    for (int t = 0; t < 256; ++t) {
        float h0 = fmaxf(fmaf(y, w1a.x, a0), 0.f);
        float h1 = fmaxf(fmaf(y, w1a.y, a1), 0.f);
        float h2 = fmaxf(fmaf(y, w1a.z, a2), 0.f);
        float h3 = fmaxf(fmaf(y, w1a.w, a3), 0.f);
        float h4 = fmaxf(fmaf(y, w1b.x, a4), 0.f);
        float h5 = fmaxf(fmaf(y, w1b.y, a5), 0.f);
        float h6 = fmaxf(fmaf(y, w1b.z, a6), 0.f);
        float h7 = fmaxf(fmaf(y, w1b.w, a7), 0.f);
        float p = pseed;
        p = fmaf(h0, w2a.x, p); p = fmaf(h1, w2a.y, p);
        p = fmaf(h2, w2a.z, p); p = fmaf(h3, w2a.w, p);
        p = fmaf(h4, w2b.x, p); p = fmaf(h5, w2b.y, p);
        p = fmaf(h6, w2b.z, p); p = fmaf(h7, w2b.w, p);
        p += swz1(p); p += swz2(p); p += swz4(p);
        const float m_ = d * y;
        if (l == 0) ybuf[r][t] = m_;
        d *= s;
        const float yn = fmaf(DT_C, v, y);   // uses v_t
        v = fmaf(DT_C, p, v);                // v_{t+1} = v_t + DT*(dot + b2)
        y = yn;
    }
    __syncthreads();

    // coalesced store: 8 lanes x float4 = 128B contiguous per pass
    const int rr = tid >> 3;
    const int cc = (tid & 7) * 4;
    float* dst = xout + ((size_t)blockIdx.x * 32 + rr) * 256 + cc;
    #pragma unroll
    for (int i = 0; i < 8; ++i) {
        *(float4*)&dst[32 * i] = *(const float4*)&ybuf[rr][cc + 32 * i];
    }
}

// ---------------------------------------------------------------------------
extern "C" void kernel_launch(void* const* d_in, const int* in_sizes, int n_in,
                              void* d_out, int out_size, void* d_ws, size_t ws_size,
                              hipStream_t stream)
{
    const float* data    = (const float*)d_in[0];
    const float* omega   = (const float*)d_in[1];
    const float* eps     = (const float*)d_in[2];
    const float* W_feat1 = (const float*)d_in[3];
    const float* b_feat1 = (const float*)d_in[4];
    const float* W_feat2 = (const float*)d_in[5];
    const float* b_feat2 = (const float*)d_in[6];
    const float* W_xim1  = (const float*)d_in[7];
    const float* b_xim1  = (const float*)d_in[8];
    const float* W_xim2  = (const float*)d_in[9];
    const float* b_xim2  = (const float*)d_in[10];
    const float* W_xil1  = (const float*)d_in[11];
    const float* b_xil1  = (const float*)d_in[12];
    const float* W_xil2  = (const float*)d_in[13];
    const float* b_xil2  = (const float*)d_in[14];
    const float* W_aux1  = (const float*)d_in[15];
    const float* b_aux1  = (const float*)d_in[16];
    const float* W_aux2  = (const float*)d_in[17];
    const float* b_aux2  = (const float*)d_in[18];

    float* out_mean  = (float*)d_out;
    float* out_lnvar = out_mean + NROWS;
    float* out_x     = out_lnvar + NROWS;

    unsigned short* wpack = (unsigned short*)d_ws;           // 3*32*256*8 bf16 = 384KB
    float* biasH = (float*)((char*)d_ws + 3 * 32 * 256 * 8 * 2);

    prep_k<<<96, 256, 0, stream>>>(W_feat1, W_feat2, W_xim1, W_xil1,
                                   b_xim1, b_xil1, wpack, biasH);
    mega_k<<<512, 256, 0, stream>>>(data, omega, wpack, biasH,
                                    b_feat1, b_feat2, W_feat1 + 256 * 256,
                                    W_xim2, b_xim2, W_xil2, b_xil2,
                                    out_mean, out_lnvar);
    ode_k<<<512, 256, 0, stream>>>(data, omega, eps, W_aux1, b_aux1,
                                   W_aux2, b_aux2, out_mean, out_lnvar, out_x);
}

// Round 3
// 148.279 us; speedup vs baseline: 1.8203x; 1.1779x over previous
//
#include <hip/hip_runtime.h>
#include <math.h>

#define NROWS 16384
#define DT_C 0.01f

typedef short s16x8 __attribute__((ext_vector_type(8)));
typedef float f32x4 __attribute__((ext_vector_type(4)));

__device__ __forceinline__ unsigned short f2bf(float f) {
    unsigned u = __float_as_uint(f);
    u += 0x7fffu + ((u >> 16) & 1u);
    return (unsigned short)(u >> 16);
}
__device__ __forceinline__ unsigned pack2bf(float a, float b) {
    return (unsigned)f2bf(a) | ((unsigned)f2bf(b) << 16);
}
__device__ __forceinline__ float swz1(float v){ return __int_as_float(__builtin_amdgcn_ds_swizzle(__float_as_int(v), 0x041F)); }
__device__ __forceinline__ float swz2(float v){ return __int_as_float(__builtin_amdgcn_ds_swizzle(__float_as_int(v), 0x081F)); }
__device__ __forceinline__ float swz4(float v){ return __int_as_float(__builtin_amdgcn_ds_swizzle(__float_as_int(v), 0x101F)); }

// ---------------------------------------------------------------------------
// Prep: pack stage-B weights to bf16 flat [stage][k8][n][8] (k = k8*8+j).
// s=0: W_feat1[0:256], s=1: W_feat2, s=2: [W_xim1 | W_xil1].
// ---------------------------------------------------------------------------
__global__ __launch_bounds__(256) void prep_k(
    const float* __restrict__ Wf1, const float* __restrict__ Wf2,
    const float* __restrict__ Wm1, const float* __restrict__ Wl1,
    const float* __restrict__ bm1, const float* __restrict__ bl1,
    unsigned short* __restrict__ wpack, float* __restrict__ biasH)
{
    const int id = blockIdx.x * 256 + threadIdx.x;   // 0..24575
    const int n  = id & 255;
    const int k8 = (id >> 8) & 31;
    const int s  = id >> 13;

    unsigned short tmp[8];
    #pragma unroll
    for (int j = 0; j < 8; ++j) {
        const int k = k8 * 8 + j;
        float v;
        if (s == 0)      v = Wf1[k * 256 + n];
        else if (s == 1) v = Wf2[k * 256 + n];
        else             v = (n < 128) ? Wm1[k * 128 + n] : Wl1[k * 128 + n - 128];
        tmp[j] = f2bf(v);
    }
    *(uint4*)&wpack[((s * 32 + k8) * 256 + n) * 8] = *(const uint4*)tmp;

    if (id < 256) biasH[id] = (id < 128) ? bm1[id] : bl1[id - 128];
}

// ---------------------------------------------------------------------------
// Mega kernel: 32-row block; h1 -> feat -> heads -> per-row dots, all in LDS.
// A-fragments stored swizzled: phys_m = m ^ (kblk & 7) to keep both the
// coalesced staging writes and the b128 frag reads conflict-light.
// ---------------------------------------------------------------------------
__global__ __launch_bounds__(256, 2) void mega_k(
    const float* __restrict__ data, const float* __restrict__ omega,
    const unsigned short* __restrict__ wpack, const float* __restrict__ biasH,
    const float* __restrict__ bf1, const float* __restrict__ bf2,
    const float* __restrict__ w256g,
    const float* __restrict__ Wm2, const float* __restrict__ bm2,
    const float* __restrict__ Wl2, const float* __restrict__ bl2,
    float* __restrict__ out_mean, float* __restrict__ out_lnvar)
{
    __shared__ unsigned short As1[8192];   // 16KB data/feat frags
    __shared__ unsigned short Hs[8192];    // 16KB h1 frags
    __shared__ unsigned short Bs[16384];   // 32KB B chunk; later heads f32
    __shared__ float omg[32];

    const int tid  = threadIdx.x;
    const int wid  = tid >> 6;
    const int lane = tid & 63;
    const int ln   = lane & 15;
    const int quad = lane >> 4;
    const int r0   = blockIdx.x * 32;

    // ---- stage A: data -> As1 (coalesced 1KB/instr loads, swizzled pack)
    {
        #pragma unroll
        for (int g2 = 0; g2 < 8; ++g2) {
            const int unit = g2 * 256 + tid;     // 16B unit over 32x256 f32
            const int m    = unit >> 6;
            const int c16  = unit & 63;
            const int kblk = c16 >> 1;
            const int h    = c16 & 1;            // 8B half within frag
            const float4 v = *(const float4*)&data[(size_t)(r0 + m) * 256 + c16 * 4];
            unsigned* d = (unsigned*)&As1[((kblk * 32) + (m ^ (kblk & 7))) * 8 + h * 4];
            d[0] = pack2bf(v.x, v.y);
            d[1] = pack2bf(v.z, v.w);
        }
        if (tid < 32) omg[tid] = omega[r0 + tid];
    }

    f32x4 acc[2][4];

    auto seed = [&](const float* bias) {
        #pragma unroll
        for (int nt = 0; nt < 4; ++nt) {
            const float b = bias[wid * 64 + nt * 16 + ln];
            acc[0][nt] = f32x4{b, b, b, b};
            acc[1][nt] = acc[0][nt];
        }
    };

    auto run_stage = [&](const unsigned short* Ap, const unsigned short* wp) {
        for (int c = 0; c < 4; ++c) {
            __syncthreads();                       // prior Bs consumers done
            {
                // coalesced: lane-contiguous 16B, 1KB per wave per instr
                const uint4* src = (const uint4*)(wp + c * 16384);
                uint4 tmp[8];
                #pragma unroll
                for (int i = 0; i < 8; ++i) tmp[i] = src[i * 256 + tid];
                #pragma unroll
                for (int i = 0; i < 8; ++i) ((uint4*)Bs)[i * 256 + tid] = tmp[i];
            }
            __syncthreads();
            #pragma unroll
            for (int kk = 0; kk < 2; ++kk) {
                const int kb   = kk * 4 + quad;
                const int kblk = c * 8 + kb;
                const int f    = kblk & 7;
                s16x8 a0 = *(const s16x8*)&Ap[(kblk * 32 + (ln ^ f)) * 8];
                s16x8 a1 = *(const s16x8*)&Ap[(kblk * 32 + ((ln ^ f) + 16)) * 8];
                #pragma unroll
                for (int nt = 0; nt < 4; ++nt) {
                    s16x8 b = *(const s16x8*)&Bs[(kb * 256 + wid * 64 + nt * 16 + ln) * 8];
                    acc[0][nt] = __builtin_amdgcn_mfma_f32_16x16x32_bf16(a0, b, acc[0][nt], 0, 0, 0);
                    acc[1][nt] = __builtin_amdgcn_mfma_f32_16x16x32_bf16(a1, b, acc[1][nt], 0, 0, 0);
                }
            }
        }
    };

    // relu + bf16 + swizzled frag store (optionally add omega rank-1 term)
    auto write_packed = [&](unsigned short* dst, bool addOm) {
        #pragma unroll
        for (int nt = 0; nt < 4; ++nt) {
            const int col = wid * 64 + nt * 16 + ln;
            const int kg  = col >> 3, f = kg & 7, jj = col & 7;
            const float wo = addOm ? w256g[col] : 0.f;
            #pragma unroll
            for (int mt = 0; mt < 2; ++mt) {
                #pragma unroll
                for (int r = 0; r < 4; ++r) {
                    const int row = mt * 16 + quad * 4 + r;
                    float v = acc[mt][nt][r];
                    if (addOm) v = fmaf(omg[row], wo, v);
                    v = fmaxf(v, 0.f);
                    dst[(kg * 32 + (row ^ f)) * 8 + jj] = f2bf(v);
                }
            }
        }
    };

    // stage 1: h1
    seed(bf1);
    run_stage(As1, wpack);
    write_packed(Hs, true);
    // stage 2: feat
    seed(bf2);
    run_stage(Hs, wpack + 65536);
    write_packed(As1, false);
    // stage 3: heads
    seed(biasH);
    run_stage(As1, wpack + 131072);
    __syncthreads();                               // all waves done reading Bs
    float* headsF = (float*)Bs;                    // [32][256], col rotated by 8*row
    #pragma unroll
    for (int nt = 0; nt < 4; ++nt) {
        const int col = wid * 64 + nt * 16 + ln;
        #pragma unroll
        for (int mt = 0; mt < 2; ++mt) {
            #pragma unroll
            for (int r = 0; r < 4; ++r) {
                const int row = mt * 16 + quad * 4 + r;
                headsF[row * 256 + ((col + row * 8) & 255)] = fmaxf(acc[mt][nt][r], 0.f);
            }
        }
    }
    __syncthreads();

    // ---- 128-dot heads: 8 lanes per row
    {
        const int m = tid >> 3, l = tid & 7;
        float pm = 0.f, pl = 0.f;
        #pragma unroll
        for (int q = 0; q < 4; ++q) {
            const int c0 = l * 16 + q * 4;
            const float4 hm = *(const float4*)&headsF[m * 256 + ((c0 + m * 8) & 255)];
            const float4 wm = *(const float4*)&Wm2[c0];
            const float4 hl = *(const float4*)&headsF[m * 256 + ((128 + c0 + m * 8) & 255)];
            const float4 wl = *(const float4*)&Wl2[c0];
            pm = fmaf(hm.w, wm.w, fmaf(hm.z, wm.z, fmaf(hm.y, wm.y, fmaf(hm.x, wm.x, pm))));
            pl = fmaf(hl.w, wl.w, fmaf(hl.z, wl.z, fmaf(hl.y, wl.y, fmaf(hl.x, wl.x, pl))));
        }
        pm += swz1(pm); pm += swz2(pm); pm += swz4(pm);
        pl += swz1(pl); pl += swz2(pl); pl += swz4(pl);
        if (l == 0) {
            const float xm = pm + bm2[0];
            out_mean[r0 + m]  = fmaxf(xm, 0.f) + log1pf(expf(-fabsf(xm)));
            out_lnvar[r0 + m] = pl + bl2[0];
        }
    }
}

// ---------------------------------------------------------------------------
// ODE scan + decay. Verlet form: y_{t+2} = 2y_{t+1} - y_t + DT^2 * acc(y_t)
// gives the swizzle-reduce one full iteration of slack. 8 lanes/row, no LDS:
// lane l captures output cols [tb*32 + l*4, +4) in registers, stores float4.
// ---------------------------------------------------------------------------
__global__ __launch_bounds__(256) void ode_k(
    const float* __restrict__ data, const float* __restrict__ omega_g,
    const float* __restrict__ eps_g,
    const float* __restrict__ W1, const float* __restrict__ b1,
    const float* __restrict__ W2, const float* __restrict__ b2p,
    const float* __restrict__ xmean, const float* __restrict__ xlnv,
    float* __restrict__ xout)
{
    const int tid = threadIdx.x;
    const int r   = tid >> 3;
    const int l   = tid & 7;
    const int row = blockIdx.x * 32 + r;

    const float4 w1a = *(const float4*)&W1[64 + l * 8];
    const float4 w1b = *(const float4*)&W1[64 + l * 8 + 4];
    const float4 w0a = *(const float4*)&W1[l * 8];
    const float4 w0b = *(const float4*)&W1[l * 8 + 4];
    const float4 bba = *(const float4*)&b1[l * 8];
    const float4 bbb = *(const float4*)&b1[l * 8 + 4];
    const float4 w2a = *(const float4*)&W2[l * 8];
    const float4 w2b = *(const float4*)&W2[l * 8 + 4];

    const float om = omega_g[row];
    const float ep = eps_g[row];
    float xi = xmean[row] + expf(0.5f * xlnv[row]) * ep;
    xi = fminf(fmaxf(xi, 0.f), 1.f);
    const float s = expf(-xi * DT_C);
    const float pseed = b2p[0] * 0.125f;

    const float A0 = fmaf(om, w0a.x, bba.x), A1 = fmaf(om, w0a.y, bba.y);
    const float A2 = fmaf(om, w0a.z, bba.z), A3 = fmaf(om, w0a.w, bba.w);
    const float A4 = fmaf(om, w0b.x, bbb.x), A5 = fmaf(om, w0b.y, bbb.y);
    const float A6 = fmaf(om, w0b.z, bbb.z), A7 = fmaf(om, w0b.w, bbb.w);

    auto partial = [&](float y) -> float {
        float h0 = fmaxf(fmaf(y, w1a.x, A0), 0.f);
        float h1 = fmaxf(fmaf(y, w1a.y, A1), 0.f);
        float h2 = fmaxf(fmaf(y, w1a.z, A2), 0.f);
        float h3 = fmaxf(fmaf(y, w1a.w, A3), 0.f);
        float h4 = fmaxf(fmaf(y, w1b.x, A4), 0.f);
        float h5 = fmaxf(fmaf(y, w1b.y, A5), 0.f);
        float h6 = fmaxf(fmaf(y, w1b.z, A6), 0.f);
        float h7 = fmaxf(fmaf(y, w1b.w, A7), 0.f);
        float pA = fmaf(h0, w2a.x, pseed);
        pA = fmaf(h1, w2a.y, pA);
        pA = fmaf(h2, w2a.z, pA);
        pA = fmaf(h3, w2a.w, pA);
        float pB = h4 * w2b.x;
        pB = fmaf(h5, w2b.y, pB);
        pB = fmaf(h6, w2b.z, pB);
        pB = fmaf(h7, w2b.w, pB);
        return pA + pB;
    };

    const float y0 = data[(size_t)row * 256];
    float ym = y0;          // y_t
    float yc = y0;          // y_{t+1} (v_0 = 0 -> y_1 = y_0)
    const float DT2 = DT_C * DT_C;

    // initial reduced acc(y_0)
    float p = partial(ym);
    p += swz1(p); p += swz2(p); p += swz4(p);
    float pr = p;

    float d = 1.f;
    float* orow = xout + (size_t)row * 256 + l * 4;

    for (int tb = 0; tb < 8; ++tb) {
        float cur[4];
        #pragma unroll
        for (int j = 0; j < 32; ++j) {
            const float m_ = d * ym;               // y_t * exp(-xi*t*DT)
            if ((j >> 2) == l) cur[j & 3] = m_;    // compile-time index
            d *= s;
            float pn = partial(yc);                // acc partial for y_{t+1}
            pn += swz1(pn); pn += swz2(pn); pn += swz4(pn);
            const float ynext = fmaf(DT2, pr, fmaf(2.f, yc, -ym));
            ym = yc; yc = ynext; pr = pn;          // reduce latency hidden by next MLP
        }
        *(float4*)&orow[tb * 32] = *(const float4*)cur;
    }
}

// ---------------------------------------------------------------------------
extern "C" void kernel_launch(void* const* d_in, const int* in_sizes, int n_in,
                              void* d_out, int out_size, void* d_ws, size_t ws_size,
                              hipStream_t stream)
{
    const float* data    = (const float*)d_in[0];
    const float* omega   = (const float*)d_in[1];
    const float* eps     = (const float*)d_in[2];
    const float* W_feat1 = (const float*)d_in[3];
    const float* b_feat1 = (const float*)d_in[4];
    const float* W_feat2 = (const float*)d_in[5];
    const float* b_feat2 = (const float*)d_in[6];
    const float* W_xim1  = (const float*)d_in[7];
    const float* b_xim1  = (const float*)d_in[8];
    const float* W_xim2  = (const float*)d_in[9];
    const float* b_xim2  = (const float*)d_in[10];
    const float* W_xil1  = (const float*)d_in[11];
    const float* b_xil1  = (const float*)d_in[12];
    const float* W_xil2  = (const float*)d_in[13];
    const float* b_xil2  = (const float*)d_in[14];
    const float* W_aux1  = (const float*)d_in[15];
    const float* b_aux1  = (const float*)d_in[16];
    const float* W_aux2  = (const float*)d_in[17];
    const float* b_aux2  = (const float*)d_in[18];

    float* out_mean  = (float*)d_out;
    float* out_lnvar = out_mean + NROWS;
    float* out_x     = out_lnvar + NROWS;

    unsigned short* wpack = (unsigned short*)d_ws;           // 384KB bf16
    float* biasH = (float*)((char*)d_ws + 3 * 32 * 256 * 8 * 2);

    prep_k<<<96, 256, 0, stream>>>(W_feat1, W_feat2, W_xim1, W_xil1,
                                   b_xim1, b_xil1, wpack, biasH);
    mega_k<<<512, 256, 0, stream>>>(data, omega, wpack, biasH,
                                    b_feat1, b_feat2, W_feat1 + 256 * 256,
                                    W_xim2, b_xim2, W_xil2, b_xil2,
                                    out_mean, out_lnvar);
    ode_k<<<512, 256, 0, stream>>>(data, omega, eps, W_aux1, b_aux1,
                                   W_aux2, b_aux2, out_mean, out_lnvar, out_x);
}

// Round 4
// 145.713 us; speedup vs baseline: 1.8523x; 1.0176x over previous
//
#include <hip/hip_runtime.h>
#include <math.h>

#define NROWS 16384
#define DT_C 0.01f

typedef short s16x8 __attribute__((ext_vector_type(8)));
typedef float f32x4 __attribute__((ext_vector_type(4)));
typedef float f32x2 __attribute__((ext_vector_type(2)));

__device__ __forceinline__ unsigned short f2bf(float f) {
    unsigned u = __float_as_uint(f);
    u += 0x7fffu + ((u >> 16) & 1u);
    return (unsigned short)(u >> 16);
}
__device__ __forceinline__ unsigned pack2bf(float a, float b) {
    return (unsigned)f2bf(a) | ((unsigned)f2bf(b) << 16);
}
__device__ __forceinline__ float swz1(float v){ return __int_as_float(__builtin_amdgcn_ds_swizzle(__float_as_int(v), 0x041F)); }
__device__ __forceinline__ float swz2(float v){ return __int_as_float(__builtin_amdgcn_ds_swizzle(__float_as_int(v), 0x081F)); }
__device__ __forceinline__ float swz4(float v){ return __int_as_float(__builtin_amdgcn_ds_swizzle(__float_as_int(v), 0x101F)); }

// ---------------------------------------------------------------------------
// Prep: pack stage-B weights to bf16 flat [stage][k8][n][8] (k = k8*8+j).
// s=0: W_feat1[0:256], s=1: W_feat2, s=2: [W_xim1 | W_xil1].
// ---------------------------------------------------------------------------
__global__ __launch_bounds__(256) void prep_k(
    const float* __restrict__ Wf1, const float* __restrict__ Wf2,
    const float* __restrict__ Wm1, const float* __restrict__ Wl1,
    const float* __restrict__ bm1, const float* __restrict__ bl1,
    unsigned short* __restrict__ wpack, float* __restrict__ biasH)
{
    const int id = blockIdx.x * 256 + threadIdx.x;   // 0..24575
    const int n  = id & 255;
    const int k8 = (id >> 8) & 31;
    const int s  = id >> 13;

    unsigned short tmp[8];
    #pragma unroll
    for (int j = 0; j < 8; ++j) {
        const int k = k8 * 8 + j;
        float v;
        if (s == 0)      v = Wf1[k * 256 + n];
        else if (s == 1) v = Wf2[k * 256 + n];
        else             v = (n < 128) ? Wm1[k * 128 + n] : Wl1[k * 128 + n - 128];
        tmp[j] = f2bf(v);
    }
    *(uint4*)&wpack[((s * 32 + k8) * 256 + n) * 8] = *(const uint4*)tmp;

    if (id < 256) biasH[id] = (id < 128) ? bm1[id] : bl1[id - 128];
}

// ---------------------------------------------------------------------------
// Fused kernel: per 32-row block:
//   phase A: h1 -> feat -> heads via MFMA; B-frags loaded DIRECTLY from
//            global (wpack, L2-resident) -> no Bs LDS, 5 barriers total.
//   phase B: per-row 128-dots -> xi_mean/xi_lnvar/xi.
//   phase C: Verlet ODE scan + decay, packed-f32 math, reg-captured output.
// ---------------------------------------------------------------------------
__global__ __launch_bounds__(256, 2) void fused_k(
    const float* __restrict__ data, const float* __restrict__ omega,
    const float* __restrict__ eps_g,
    const unsigned short* __restrict__ wpack, const float* __restrict__ biasH,
    const float* __restrict__ bf1, const float* __restrict__ bf2,
    const float* __restrict__ w256g,
    const float* __restrict__ Wm2, const float* __restrict__ bm2,
    const float* __restrict__ Wl2, const float* __restrict__ bl2,
    const float* __restrict__ Wa1, const float* __restrict__ ba1,
    const float* __restrict__ Wa2, const float* __restrict__ ba2,
    float* __restrict__ out_mean, float* __restrict__ out_lnvar,
    float* __restrict__ xout)
{
    __shared__ unsigned short As1[8192];   // 16KB frags: data, then feat
    __shared__ unsigned short Hs[8192];    // 16KB frags: h1
    __shared__ float headsF[32 * 256];     // 32KB: heads f32, col-rotated
    __shared__ float omg[32];
    __shared__ float xiS[32];

    const int tid  = threadIdx.x;
    const int wid  = tid >> 6;
    const int lane = tid & 63;
    const int ln   = lane & 15;
    const int quad = lane >> 4;
    const int r0   = blockIdx.x * 32;

    // ---- stage data -> As1 (coalesced, swizzled frag pack)
    {
        #pragma unroll
        for (int g2 = 0; g2 < 8; ++g2) {
            const int unit = g2 * 256 + tid;     // 16B unit over 32x256 f32
            const int m    = unit >> 6;
            const int c16  = unit & 63;
            const int kblk = c16 >> 1;
            const int h    = c16 & 1;
            const float4 v = *(const float4*)&data[(size_t)(r0 + m) * 256 + c16 * 4];
            unsigned* d = (unsigned*)&As1[((kblk * 32) + (m ^ (kblk & 7))) * 8 + h * 4];
            d[0] = pack2bf(v.x, v.y);
            d[1] = pack2bf(v.z, v.w);
        }
        if (tid < 32) omg[tid] = omega[r0 + tid];
    }

    f32x4 acc[2][4];

    auto seed = [&](const float* bias) {
        #pragma unroll
        for (int nt = 0; nt < 4; ++nt) {
            const float b = bias[wid * 64 + nt * 16 + ln];
            acc[0][nt] = f32x4{b, b, b, b};
            acc[1][nt] = acc[0][nt];
        }
    };

    // K-loop: A-frags from LDS, B-frags straight from global (no barriers)
    auto run_stage = [&](const unsigned short* Ap, const unsigned short* wp) {
        #pragma unroll
        for (int c = 0; c < 4; ++c) {
            #pragma unroll
            for (int kk = 0; kk < 2; ++kk) {
                const int kb   = kk * 4 + quad;
                const int kblk = c * 8 + kb;
                const int f    = kblk & 7;
                s16x8 b0 = *(const s16x8*)&wp[((size_t)(kblk * 256) + wid * 64 + 0 * 16 + ln) * 8];
                s16x8 b1 = *(const s16x8*)&wp[((size_t)(kblk * 256) + wid * 64 + 1 * 16 + ln) * 8];
                s16x8 b2 = *(const s16x8*)&wp[((size_t)(kblk * 256) + wid * 64 + 2 * 16 + ln) * 8];
                s16x8 b3 = *(const s16x8*)&wp[((size_t)(kblk * 256) + wid * 64 + 3 * 16 + ln) * 8];
                s16x8 a0 = *(const s16x8*)&Ap[(kblk * 32 + (ln ^ f)) * 8];
                s16x8 a1 = *(const s16x8*)&Ap[(kblk * 32 + ((ln ^ f) + 16)) * 8];
                acc[0][0] = __builtin_amdgcn_mfma_f32_16x16x32_bf16(a0, b0, acc[0][0], 0, 0, 0);
                acc[1][0] = __builtin_amdgcn_mfma_f32_16x16x32_bf16(a1, b0, acc[1][0], 0, 0, 0);
                acc[0][1] = __builtin_amdgcn_mfma_f32_16x16x32_bf16(a0, b1, acc[0][1], 0, 0, 0);
                acc[1][1] = __builtin_amdgcn_mfma_f32_16x16x32_bf16(a1, b1, acc[1][1], 0, 0, 0);
                acc[0][2] = __builtin_amdgcn_mfma_f32_16x16x32_bf16(a0, b2, acc[0][2], 0, 0, 0);
                acc[1][2] = __builtin_amdgcn_mfma_f32_16x16x32_bf16(a1, b2, acc[1][2], 0, 0, 0);
                acc[0][3] = __builtin_amdgcn_mfma_f32_16x16x32_bf16(a0, b3, acc[0][3], 0, 0, 0);
                acc[1][3] = __builtin_amdgcn_mfma_f32_16x16x32_bf16(a1, b3, acc[1][3], 0, 0, 0);
            }
        }
    };

    auto write_packed = [&](unsigned short* dst, bool addOm) {
        #pragma unroll
        for (int nt = 0; nt < 4; ++nt) {
            const int col = wid * 64 + nt * 16 + ln;
            const int kg  = col >> 3, f = kg & 7, jj = col & 7;
            const float wo = addOm ? w256g[col] : 0.f;
            #pragma unroll
            for (int mt = 0; mt < 2; ++mt) {
                #pragma unroll
                for (int r = 0; r < 4; ++r) {
                    const int row = mt * 16 + quad * 4 + r;
                    float v = acc[mt][nt][r];
                    if (addOm) v = fmaf(omg[row], wo, v);
                    v = fmaxf(v, 0.f);
                    dst[(kg * 32 + (row ^ f)) * 8 + jj] = f2bf(v);
                }
            }
        }
    };

    __syncthreads();                               // B0: As1(data), omg ready
    seed(bf1);
    run_stage(As1, wpack);
    write_packed(Hs, true);
    __syncthreads();                               // B1: Hs ready
    seed(bf2);
    run_stage(Hs, wpack + 65536);
    write_packed(As1, false);
    __syncthreads();                               // B2: As1(feat) ready
    seed(biasH);
    run_stage(As1, wpack + 131072);
    #pragma unroll
    for (int nt = 0; nt < 4; ++nt) {
        const int col = wid * 64 + nt * 16 + ln;
        #pragma unroll
        for (int mt = 0; mt < 2; ++mt) {
            #pragma unroll
            for (int r = 0; r < 4; ++r) {
                const int row = mt * 16 + quad * 4 + r;
                headsF[row * 256 + ((col + row * 8) & 255)] = fmaxf(acc[mt][nt][r], 0.f);
            }
        }
    }
    __syncthreads();                               // B3: heads ready

    // ---- phase B: 128-dot heads, 8 lanes/row
    {
        const int m = tid >> 3, l = tid & 7;
        float pm = 0.f, pl = 0.f;
        #pragma unroll
        for (int q = 0; q < 4; ++q) {
            const int c0 = l * 16 + q * 4;
            const float4 hm = *(const float4*)&headsF[m * 256 + ((c0 + m * 8) & 255)];
            const float4 wm = *(const float4*)&Wm2[c0];
            const float4 hl = *(const float4*)&headsF[m * 256 + ((128 + c0 + m * 8) & 255)];
            const float4 wl = *(const float4*)&Wl2[c0];
            pm = fmaf(hm.w, wm.w, fmaf(hm.z, wm.z, fmaf(hm.y, wm.y, fmaf(hm.x, wm.x, pm))));
            pl = fmaf(hl.w, wl.w, fmaf(hl.z, wl.z, fmaf(hl.y, wl.y, fmaf(hl.x, wl.x, pl))));
        }
        pm += swz1(pm); pm += swz2(pm); pm += swz4(pm);
        pl += swz1(pl); pl += swz2(pl); pl += swz4(pl);
        if (l == 0) {
            const float xm  = pm + bm2[0];
            const float mean = fmaxf(xm, 0.f) + log1pf(expf(-fabsf(xm)));
            const float lnv  = pl + bl2[0];
            out_mean[r0 + m]  = mean;
            out_lnvar[r0 + m] = lnv;
            float xi = mean + expf(0.5f * lnv) * eps_g[r0 + m];
            xiS[m] = fminf(fmaxf(xi, 0.f), 1.f);
        }
    }
    __syncthreads();                               // B4: xiS ready

    // ---- phase C: Verlet ODE + decay, packed f32
    {
        const int r   = tid >> 3;
        const int l   = tid & 7;
        const int row = r0 + r;
        const float om = omg[r];
        const float xi = xiS[r];
        const float s  = expf(-xi * DT_C);
        const float pseed = ba2[0] * 0.125f;

        f32x2 w1v[4], Av[4], w2v[4];
        #pragma unroll
        for (int i = 0; i < 4; ++i) {
            const f32x2 w0 = *(const f32x2*)&Wa1[l * 8 + i * 2];
            const f32x2 bb = *(const f32x2*)&ba1[l * 8 + i * 2];
            w1v[i] = *(const f32x2*)&Wa1[64 + l * 8 + i * 2];
            w2v[i] = *(const f32x2*)&Wa2[l * 8 + i * 2];
            Av[i]  = f32x2{fmaf(om, w0.x, bb.x), fmaf(om, w0.y, bb.y)};
        }

        auto partial = [&](float y) -> float {
            const f32x2 y2 = f32x2{y, y};
            f32x2 acc2 = f32x2{pseed, 0.f};
            #pragma unroll
            for (int i = 0; i < 4; ++i) {
                f32x2 h = __builtin_elementwise_fma(y2, w1v[i], Av[i]);
                h = __builtin_elementwise_max(h, f32x2{0.f, 0.f});
                acc2 = __builtin_elementwise_fma(h, w2v[i], acc2);
            }
            return acc2.x + acc2.y;
        };

        const float y0 = data[(size_t)row * 256];
        float ym = y0;          // y_t
        float yc = y0;          // y_{t+1}  (v0 = 0)
        const float DT2 = DT_C * DT_C;

        float p = partial(ym);
        p += swz1(p); p += swz2(p); p += swz4(p);
        float pr = p;

        float d = 1.f;
        float* orow = xout + (size_t)row * 256 + l * 4;

        for (int tb = 0; tb < 8; ++tb) {
            float cur[4];
            #pragma unroll
            for (int j = 0; j < 32; ++j) {
                const float m_ = d * ym;
                if ((j >> 2) == l) cur[j & 3] = m_;    // compile-time index
                d *= s;
                float pn = partial(yc);
                pn += swz1(pn); pn += swz2(pn); pn += swz4(pn);
                const float ynext = fmaf(DT2, pr, fmaf(2.f, yc, -ym));
                ym = yc; yc = ynext; pr = pn;
            }
            *(float4*)&orow[tb * 32] = *(const float4*)cur;
        }
    }
}

// ---------------------------------------------------------------------------
extern "C" void kernel_launch(void* const* d_in, const int* in_sizes, int n_in,
                              void* d_out, int out_size, void* d_ws, size_t ws_size,
                              hipStream_t stream)
{
    const float* data    = (const float*)d_in[0];
    const float* omega   = (const float*)d_in[1];
    const float* eps     = (const float*)d_in[2];
    const float* W_feat1 = (const float*)d_in[3];
    const float* b_feat1 = (const float*)d_in[4];
    const float* W_feat2 = (const float*)d_in[5];
    const float* b_feat2 = (const float*)d_in[6];
    const float* W_xim1  = (const float*)d_in[7];
    const float* b_xim1  = (const float*)d_in[8];
    const float* W_xim2  = (const float*)d_in[9];
    const float* b_xim2  = (const float*)d_in[10];
    const float* W_xil1  = (const float*)d_in[11];
    const float* b_xil1  = (const float*)d_in[12];
    const float* W_xil2  = (const float*)d_in[13];
    const float* b_xil2  = (const float*)d_in[14];
    const float* W_aux1  = (const float*)d_in[15];
    const float* b_aux1  = (const float*)d_in[16];
    const float* W_aux2  = (const float*)d_in[17];
    const float* b_aux2  = (const float*)d_in[18];

    float* out_mean  = (float*)d_out;
    float* out_lnvar = out_mean + NROWS;
    float* out_x     = out_lnvar + NROWS;

    unsigned short* wpack = (unsigned short*)d_ws;           // 384KB bf16
    float* biasH = (float*)((char*)d_ws + 3 * 32 * 256 * 8 * 2);

    prep_k<<<96, 256, 0, stream>>>(W_feat1, W_feat2, W_xim1, W_xil1,
                                   b_xim1, b_xil1, wpack, biasH);
    fused_k<<<512, 256, 0, stream>>>(data, omega, eps, wpack, biasH,
                                     b_feat1, b_feat2, W_feat1 + 256 * 256,
                                     W_xim2, b_xim2, W_xil2, b_xil2,
                                     W_aux1, b_aux1, W_aux2, b_aux2,
                                     out_mean, out_lnvar, out_x);
}

// Round 5
// 139.890 us; speedup vs baseline: 1.9294x; 1.0416x over previous
//
#include <hip/hip_runtime.h>
#include <math.h>

#define NROWS 16384
#define DT_C 0.01f

typedef short s16x8 __attribute__((ext_vector_type(8)));
typedef float f32x4 __attribute__((ext_vector_type(4)));
typedef float f32x2 __attribute__((ext_vector_type(2)));

__device__ __forceinline__ unsigned short f2bf(float f) {
    unsigned u = __float_as_uint(f);
    u += 0x7fffu + ((u >> 16) & 1u);
    return (unsigned short)(u >> 16);
}
__device__ __forceinline__ unsigned pack2bf(float a, float b) {
    return (unsigned)f2bf(a) | ((unsigned)f2bf(b) << 16);
}
// VALU-pipe cross-lane adds via DPP (no LDS pipe, ~4cyc latency each).
// 8-lane sum: xor1 (quad_perm [1,0,3,2]=0xB1), xor2 (quad_perm [2,3,0,1]=0x4E),
// then row_half_mirror (0x141, lane i<->i^7 within 8) completes the sum.
template <int CTRL>
__device__ __forceinline__ float dppadd(float v) {
    int x = __builtin_amdgcn_update_dpp(0, __float_as_int(v), CTRL, 0xF, 0xF, true);
    return v + __int_as_float(x);
}
__device__ __forceinline__ float sum8(float p) {
    p = dppadd<0xB1>(p);
    p = dppadd<0x4E>(p);
    p = dppadd<0x141>(p);
    return p;
}

// ---------------------------------------------------------------------------
// Prep: pack stage-B weights to bf16 flat [stage][k8][n][8] (k = k8*8+j).
// s=0: W_feat1[0:256], s=1: W_feat2, s=2: [W_xim1 | W_xil1].
// ---------------------------------------------------------------------------
__global__ __launch_bounds__(256) void prep_k(
    const float* __restrict__ Wf1, const float* __restrict__ Wf2,
    const float* __restrict__ Wm1, const float* __restrict__ Wl1,
    const float* __restrict__ bm1, const float* __restrict__ bl1,
    unsigned short* __restrict__ wpack, float* __restrict__ biasH)
{
    const int id = blockIdx.x * 256 + threadIdx.x;   // 0..24575
    const int n  = id & 255;
    const int k8 = (id >> 8) & 31;
    const int s  = id >> 13;

    unsigned short tmp[8];
    #pragma unroll
    for (int j = 0; j < 8; ++j) {
        const int k = k8 * 8 + j;
        float v;
        if (s == 0)      v = Wf1[k * 256 + n];
        else if (s == 1) v = Wf2[k * 256 + n];
        else             v = (n < 128) ? Wm1[k * 128 + n] : Wl1[k * 128 + n - 128];
        tmp[j] = f2bf(v);
    }
    *(uint4*)&wpack[((s * 32 + k8) * 256 + n) * 8] = *(const uint4*)tmp;

    if (id < 256) biasH[id] = (id < 128) ? bm1[id] : bl1[id - 128];
}

// ---------------------------------------------------------------------------
// Fused kernel, per 32-row block:
//   stage data->LDS frags; ODE scan (xi-independent!) -> raw y to xout;
//   MFMA h1->feat->heads (B direct from L2-resident wpack);
//   per-row 128-dots -> xi; epilogue: decay xout in place via expf.
// ---------------------------------------------------------------------------
__global__ __launch_bounds__(256, 2) void fused_k(
    const float* __restrict__ data, const float* __restrict__ omega,
    const float* __restrict__ eps_g,
    const unsigned short* __restrict__ wpack, const float* __restrict__ biasH,
    const float* __restrict__ bf1, const float* __restrict__ bf2,
    const float* __restrict__ w256g,
    const float* __restrict__ Wm2, const float* __restrict__ bm2,
    const float* __restrict__ Wl2, const float* __restrict__ bl2,
    const float* __restrict__ Wa1, const float* __restrict__ ba1,
    const float* __restrict__ Wa2, const float* __restrict__ ba2,
    float* __restrict__ out_mean, float* __restrict__ out_lnvar,
    float* __restrict__ xout)
{
    // 32.25KB LDS: headsF aliases As1+Hs (dead by heads phase)
    __shared__ __align__(16) unsigned char smem[33024];
    unsigned short* As1 = (unsigned short*)smem;            // 16KB frags: data, then feat
    unsigned short* Hs  = (unsigned short*)(smem + 16384);  // 16KB frags: h1
    float* headsF = (float*)smem;                           // 32KB alias: heads f32
    float* omg = (float*)(smem + 32768);
    float* xiS = omg + 32;

    const int tid  = threadIdx.x;
    const int wid  = tid >> 6;
    const int lane = tid & 63;
    const int ln   = lane & 15;
    const int quad = lane >> 4;
    const int r0   = blockIdx.x * 32;

    // ---- stage data -> As1 (coalesced, swizzled frag pack)
    {
        #pragma unroll
        for (int g2 = 0; g2 < 8; ++g2) {
            const int unit = g2 * 256 + tid;     // 16B unit over 32x256 f32
            const int m    = unit >> 6;
            const int c16  = unit & 63;
            const int kblk = c16 >> 1;
            const int h    = c16 & 1;
            const float4 v = *(const float4*)&data[(size_t)(r0 + m) * 256 + c16 * 4];
            unsigned* d = (unsigned*)&As1[((kblk * 32) + (m ^ (kblk & 7))) * 8 + h * 4];
            d[0] = pack2bf(v.x, v.y);
            d[1] = pack2bf(v.z, v.w);
        }
        if (tid < 32) omg[tid] = omega[r0 + tid];
    }
    __syncthreads();                               // B0: As1 + omg ready

    // ---- ODE scan (independent of xi): raw y_t -> xout
    {
        const int r   = tid >> 3;
        const int l   = tid & 7;
        const int row = r0 + r;
        const float om = omg[r];
        const float pseed = ba2[0] * 0.125f;

        f32x2 w1v[4], Av[4], w2v[4];
        #pragma unroll
        for (int i = 0; i < 4; ++i) {
            const f32x2 w0 = *(const f32x2*)&Wa1[l * 8 + i * 2];
            const f32x2 bb = *(const f32x2*)&ba1[l * 8 + i * 2];
            w1v[i] = *(const f32x2*)&Wa1[64 + l * 8 + i * 2];
            w2v[i] = *(const f32x2*)&Wa2[l * 8 + i * 2];
            Av[i]  = f32x2{fmaf(om, w0.x, bb.x), fmaf(om, w0.y, bb.y)};
        }

        auto partial = [&](float y) -> float {
            const f32x2 y2 = f32x2{y, y};
            f32x2 acc2 = f32x2{pseed, 0.f};
            #pragma unroll
            for (int i = 0; i < 4; ++i) {
                f32x2 h = __builtin_elementwise_fma(y2, w1v[i], Av[i]);
                h = __builtin_elementwise_max(h, f32x2{0.f, 0.f});
                acc2 = __builtin_elementwise_fma(h, w2v[i], acc2);
            }
            return acc2.x + acc2.y;
        };

        const float y0 = data[(size_t)row * 256];
        float ym = y0;          // y_t
        float yc = y0;          // y_{t+1}  (v0 = 0)
        const float DT2 = DT_C * DT_C;
        float pr = sum8(partial(ym));

        float* orow = xout + (size_t)row * 256 + l * 4;
        for (int tb = 0; tb < 8; ++tb) {
            float cur[4];
            #pragma unroll
            for (int j = 0; j < 32; ++j) {
                if ((j >> 2) == l) cur[j & 3] = ym;    // compile-time index
                float pn = sum8(partial(yc));
                const float ynext = fmaf(DT2, pr, fmaf(2.f, yc, -ym));
                ym = yc; yc = ynext; pr = pn;          // pr consumed next step
            }
            *(float4*)&orow[tb * 32] = *(const float4*)cur;   // raw (undecayed)
        }
    }

    // ---- MFMA phases
    f32x4 acc[2][4];

    auto seed = [&](const float* bias) {
        #pragma unroll
        for (int nt = 0; nt < 4; ++nt) {
            const float b = bias[wid * 64 + nt * 16 + ln];
            acc[0][nt] = f32x4{b, b, b, b};
            acc[1][nt] = acc[0][nt];
        }
    };

    // A-frags from LDS, B-frags straight from global (L2-resident)
    auto run_stage = [&](const unsigned short* Ap, const unsigned short* wp) {
        #pragma unroll
        for (int c = 0; c < 4; ++c) {
            #pragma unroll
            for (int kk = 0; kk < 2; ++kk) {
                const int kb   = kk * 4 + quad;
                const int kblk = c * 8 + kb;
                const int f    = kblk & 7;
                s16x8 b0 = *(const s16x8*)&wp[((size_t)(kblk * 256) + wid * 64 + 0 * 16 + ln) * 8];
                s16x8 b1 = *(const s16x8*)&wp[((size_t)(kblk * 256) + wid * 64 + 1 * 16 + ln) * 8];
                s16x8 b2 = *(const s16x8*)&wp[((size_t)(kblk * 256) + wid * 64 + 2 * 16 + ln) * 8];
                s16x8 b3 = *(const s16x8*)&wp[((size_t)(kblk * 256) + wid * 64 + 3 * 16 + ln) * 8];
                s16x8 a0 = *(const s16x8*)&Ap[(kblk * 32 + (ln ^ f)) * 8];
                s16x8 a1 = *(const s16x8*)&Ap[(kblk * 32 + ((ln ^ f) + 16)) * 8];
                acc[0][0] = __builtin_amdgcn_mfma_f32_16x16x32_bf16(a0, b0, acc[0][0], 0, 0, 0);
                acc[1][0] = __builtin_amdgcn_mfma_f32_16x16x32_bf16(a1, b0, acc[1][0], 0, 0, 0);
                acc[0][1] = __builtin_amdgcn_mfma_f32_16x16x32_bf16(a0, b1, acc[0][1], 0, 0, 0);
                acc[1][1] = __builtin_amdgcn_mfma_f32_16x16x32_bf16(a1, b1, acc[1][1], 0, 0, 0);
                acc[0][2] = __builtin_amdgcn_mfma_f32_16x16x32_bf16(a0, b2, acc[0][2], 0, 0, 0);
                acc[1][2] = __builtin_amdgcn_mfma_f32_16x16x32_bf16(a1, b2, acc[1][2], 0, 0, 0);
                acc[0][3] = __builtin_amdgcn_mfma_f32_16x16x32_bf16(a0, b3, acc[0][3], 0, 0, 0);
                acc[1][3] = __builtin_amdgcn_mfma_f32_16x16x32_bf16(a1, b3, acc[1][3], 0, 0, 0);
            }
        }
    };

    auto write_packed = [&](unsigned short* dst, bool addOm) {
        #pragma unroll
        for (int nt = 0; nt < 4; ++nt) {
            const int col = wid * 64 + nt * 16 + ln;
            const int kg  = col >> 3, f = kg & 7, jj = col & 7;
            const float wo = addOm ? w256g[col] : 0.f;
            #pragma unroll
            for (int mt = 0; mt < 2; ++mt) {
                #pragma unroll
                for (int r = 0; r < 4; ++r) {
                    const int row = mt * 16 + quad * 4 + r;
                    float v = acc[mt][nt][r];
                    if (addOm) v = fmaf(omg[row], wo, v);
                    v = fmaxf(v, 0.f);
                    dst[(kg * 32 + (row ^ f)) * 8 + jj] = f2bf(v);
                }
            }
        }
    };

    seed(bf1);
    run_stage(As1, wpack);
    write_packed(Hs, true);
    __syncthreads();                               // B1: Hs ready
    seed(bf2);
    run_stage(Hs, wpack + 65536);
    write_packed(As1, false);
    __syncthreads();                               // B2: As1(feat) ready
    seed(biasH);
    run_stage(As1, wpack + 131072);
    __syncthreads();                               // B3a: all waves done with As1/Hs (alias!)
    #pragma unroll
    for (int nt = 0; nt < 4; ++nt) {
        const int col = wid * 64 + nt * 16 + ln;
        #pragma unroll
        for (int mt = 0; mt < 2; ++mt) {
            #pragma unroll
            for (int r = 0; r < 4; ++r) {
                const int row = mt * 16 + quad * 4 + r;
                headsF[row * 256 + ((col + row * 8) & 255)] = fmaxf(acc[mt][nt][r], 0.f);
            }
        }
    }
    __syncthreads();                               // B3: heads ready

    // ---- 128-dot heads: 8 lanes/row -> xi
    {
        const int m = tid >> 3, l = tid & 7;
        float pm = 0.f, pl = 0.f;
        #pragma unroll
        for (int q = 0; q < 4; ++q) {
            const int c0 = l * 16 + q * 4;
            const float4 hm = *(const float4*)&headsF[m * 256 + ((c0 + m * 8) & 255)];
            const float4 wm = *(const float4*)&Wm2[c0];
            const float4 hl = *(const float4*)&headsF[m * 256 + ((128 + c0 + m * 8) & 255)];
            const float4 wl = *(const float4*)&Wl2[c0];
            pm = fmaf(hm.w, wm.w, fmaf(hm.z, wm.z, fmaf(hm.y, wm.y, fmaf(hm.x, wm.x, pm))));
            pl = fmaf(hl.w, wl.w, fmaf(hl.z, wl.z, fmaf(hl.y, wl.y, fmaf(hl.x, wl.x, pl))));
        }
        pm = sum8(pm);
        pl = sum8(pl);
        if (l == 0) {
            const float xm  = pm + bm2[0];
            const float mean = fmaxf(xm, 0.f) + log1pf(expf(-fabsf(xm)));
            const float lnv  = pl + bl2[0];
            out_mean[r0 + m]  = mean;
            out_lnvar[r0 + m] = lnv;
            float xi = mean + expf(0.5f * lnv) * eps_g[r0 + m];
            xiS[m] = fminf(fmaxf(xi, 0.f), 1.f);
        }
    }
    __syncthreads();                               // B4: xiS ready

    // ---- epilogue: apply decay in place (xout rows are L2-hot, 33KB/block)
    {
        const int r   = tid >> 3;
        const int l   = tid & 7;
        const float nxdt = -xiS[r] * DT_C;
        float* orow = xout + (size_t)(r0 + r) * 256 + l * 4;
        #pragma unroll
        for (int tb = 0; tb < 8; ++tb) {
            float4 v = *(const float4*)&orow[tb * 32];
            const int c0 = tb * 32 + l * 4;
            v.x *= __expf(nxdt * (float)(c0 + 0));
            v.y *= __expf(nxdt * (float)(c0 + 1));
            v.z *= __expf(nxdt * (float)(c0 + 2));
            v.w *= __expf(nxdt * (float)(c0 + 3));
            *(float4*)&orow[tb * 32] = v;
        }
    }
}

// ---------------------------------------------------------------------------
extern "C" void kernel_launch(void* const* d_in, const int* in_sizes, int n_in,
                              void* d_out, int out_size, void* d_ws, size_t ws_size,
                              hipStream_t stream)
{
    const float* data    = (const float*)d_in[0];
    const float* omega   = (const float*)d_in[1];
    const float* eps     = (const float*)d_in[2];
    const float* W_feat1 = (const float*)d_in[3];
    const float* b_feat1 = (const float*)d_in[4];
    const float* W_feat2 = (const float*)d_in[5];
    const float* b_feat2 = (const float*)d_in[6];
    const float* W_xim1  = (const float*)d_in[7];
    const float* b_xim1  = (const float*)d_in[8];
    const float* W_xim2  = (const float*)d_in[9];
    const float* b_xim2  = (const float*)d_in[10];
    const float* W_xil1  = (const float*)d_in[11];
    const float* b_xil1  = (const float*)d_in[12];
    const float* W_xil2  = (const float*)d_in[13];
    const float* b_xil2  = (const float*)d_in[14];
    const float* W_aux1  = (const float*)d_in[15];
    const float* b_aux1  = (const float*)d_in[16];
    const float* W_aux2  = (const float*)d_in[17];
    const float* b_aux2  = (const float*)d_in[18];

    float* out_mean  = (float*)d_out;
    float* out_lnvar = out_mean + NROWS;
    float* out_x     = out_lnvar + NROWS;

    unsigned short* wpack = (unsigned short*)d_ws;           // 384KB bf16
    float* biasH = (float*)((char*)d_ws + 3 * 32 * 256 * 8 * 2);

    prep_k<<<96, 256, 0, stream>>>(W_feat1, W_feat2, W_xim1, W_xil1,
                                   b_xim1, b_xil1, wpack, biasH);
    fused_k<<<512, 256, 0, stream>>>(data, omega, eps, wpack, biasH,
                                     b_feat1, b_feat2, W_feat1 + 256 * 256,
                                     W_xim2, b_xim2, W_xil2, b_xil2,
                                     W_aux1, b_aux1, W_aux2, b_aux2,
                                     out_mean, out_lnvar, out_x);
}